// Round 10
// baseline (138.989 us; speedup 1.0000x reference)
//
#include <hip/hip_runtime.h>

typedef unsigned short ushort_t;
typedef unsigned int uint_t;

typedef __bf16 bf16x8 __attribute__((ext_vector_type(8)));
typedef float f32x4 __attribute__((ext_vector_type(4)));

#define KK 588       // true K
#define KP 608       // padded K (19 * 32)
#define NN 1152      // N (output cols)
#define MM 32768     // M (output rows)
#define POSROWS 4096 // h*w per image
#define BMT 256      // block tile M
#define BNT 128      // block tile N
#define NFULL 9      // full BK=64 K-tiles (k 0..575)
#define KTAIL 576    // tail k0 (32 wide)
#define GRID 1152    // 8 xcd * 2 pp * 9 nt * 8 r
#define CHUNKS_PER_ROW 76                    // KP/8
#define ACHUNKS (MM * CHUNKS_PER_ROW)        // 2,490,368
#define ABLOCKS (ACHUNKS / 256)              // 9728
#define BCHUNKS (NN * CHUNKS_PER_ROW)        // 87552
#define BBLOCKS ((BCHUNKS + 255) / 256)      // 342

#define AS1 __attribute__((address_space(1)))
#define AS3 __attribute__((address_space(3)))

// ---------------- helpers ----------------

__device__ __forceinline__ void cubic_taps(int dst, float* w, int* idx) {
    const float A = -0.75f;
    float src = (float)dst * 0.25f - 0.25f;   // (dst+0.5)*16/64 - 0.5
    int x0 = (int)floorf(src);
    #pragma unroll
    for (int k = -1; k <= 2; ++k) {
        int i = x0 + k;
        int ic = i < 0 ? 0 : (i > 15 ? 15 : i);
        float d = fabsf(src - (float)i);
        float wt;
        if (d <= 1.0f)      wt = ((A + 2.0f) * d - (A + 3.0f)) * d * d + 1.0f;
        else if (d < 2.0f)  wt = ((A * d - 5.0f * A) * d + 8.0f * A) * d - 4.0f * A;
        else                wt = 0.0f;
        w[k + 1] = wt;
        idx[k + 1] = ic;
    }
}

__device__ __forceinline__ void cvt_chunk(const float* __restrict__ src,
                                          ushort_t* __restrict__ dst, int c) {
    int row = c / CHUNKS_PER_ROW;
    int k0 = (c - row * CHUNKS_PER_ROW) * 8;
    const float* g = src + (size_t)row * KK + k0;
    bf16x8 v;
    if (k0 + 8 <= KK) {
        f32x4 a = *(const f32x4*)g;
        f32x4 b = *(const f32x4*)(g + 4);
        #pragma unroll
        for (int e = 0; e < 4; ++e) { v[e] = (__bf16)a[e]; v[e + 4] = (__bf16)b[e]; }
    } else {
        #pragma unroll
        for (int e = 0; e < 8; ++e)
            v[e] = (k0 + e < KK) ? (__bf16)g[e] : (__bf16)0.f;
    }
    *(bf16x8*)(dst + (size_t)row * KP + k0) = v;
}

// ---------------- prep: cvt A + cvt B (fp32->bf16, pad) + pos table (+bias) ----------------

__global__ void prep_kernel(const float* __restrict__ pv, ushort_t* __restrict__ pvb,
                            const float* __restrict__ wp, ushort_t* __restrict__ wb,
                            const float* __restrict__ pt, const float* __restrict__ bias,
                            float* __restrict__ pos) {
    int b = blockIdx.x;
    if (b < ABLOCKS) {
        cvt_chunk(pv, pvb, b * 256 + threadIdx.x);
    } else if (b < ABLOCKS + BBLOCKS) {
        int c = (b - ABLOCKS) * 256 + threadIdx.x;
        if (c < BCHUNKS) cvt_chunk(wp, wb, c);
    } else {
        // pos row (rearranged) with bias folded in
        int n = b - (ABLOCKS + BBLOCKS); // 0..4095
        int h = ((n >> 7) << 1) | ((n >> 1) & 1);
        int w = (((n >> 2) & 31) << 1) | (n & 1);
        float wh[4], ww[4];
        int ih[4], iw[4];
        cubic_taps(h, wh, ih);
        cubic_taps(w, ww, iw);
        const f32x4* pt4 = (const f32x4*)pt;
        const f32x4* bias4 = (const f32x4*)bias;
        for (int j = threadIdx.x; j < NN / 4; j += blockDim.x) {
            f32x4 s = bias4[j];
            #pragma unroll
            for (int a = 0; a < 4; ++a) {
                #pragma unroll
                for (int bq = 0; bq < 4; ++bq) {
                    float wt = wh[a] * ww[bq];
                    f32x4 vv = pt4[(ih[a] * 16 + iw[bq]) * (NN / 4) + j];
                    s.x += wt * vv.x; s.y += wt * vv.y; s.z += wt * vv.z; s.w += wt * vv.w;
                }
            }
            ((f32x4*)pos)[(size_t)n * (NN / 4) + j] = s;
        }
    }
}

// ---------------- 8-phase-style bf16 MFMA GEMM + pos epilogue ----------------
// 256x128 tile, BK=64, 512 threads = 8 waves (4M x 2N), wave tile 64x64.
// Per K-tile: top {2 stage, vmcnt(2), barrier} + 4 phases of
// {ds_reads || stage, lgkm0, setprio, 8 MFMA, barrier}. Counted vmcnt only --
// next tile's 6 loads stay in flight across all barriers (T3+T4+T5).

#define MFMA_(MI,NI,AR,KH) acc[MI][NI] = __builtin_amdgcn_mfma_f32_16x16x32_bf16( \
    bfr[NI][KH], af[AR][KH], acc[MI][NI], 0, 0, 0);
// tail variant: B has only kh=0 (32-wide tail); af's 2nd idx is the mi selector
#define MFMT_(MI,NI,AR,AH) acc[MI][NI] = __builtin_amdgcn_mfma_f32_16x16x32_bf16( \
    bfr[NI][0], af[AR][AH], acc[MI][NI], 0, 0, 0);

__global__ __launch_bounds__(512, 2)
void gemm_kernel(const ushort_t* __restrict__ Abf,
                 const ushort_t* __restrict__ Bbf,
                 const float* __restrict__ pos,
                 float* __restrict__ out) {
    __shared__ __align__(16) ushort_t lA[2][BMT * 64]; // 32KB/buf, 128B rows, slot^row&7
    __shared__ __align__(16) ushort_t lB[2][BNT * 64]; // 16KB/buf
    __shared__ __align__(16) ushort_t lAt[BMT * 32];   // 16KB tail (64B rows)
    __shared__ __align__(16) ushort_t lBt[BNT * 32];   // 8KB tail

    const int t = threadIdx.x;
    const int lane = t & 63;
    const int lm = lane & 15;
    const int lq = lane >> 4;
    const int wid = t >> 6;    // 0..7
    const int wm = wid >> 1;   // 0..3
    const int wn = wid & 1;    // 0..1

    // reuse-aware bijective swizzle (same as R8: FETCH 57MB verified)
    int blk = (int)blockIdx.x;
    int xcd = blk & 7;
    int local = blk >> 3;        // 0..143
    int pp = local / 72;         // 0..1
    int rem = local - pp * 72;   // 0..71
    int nt = rem >> 3;           // 0..8
    int r  = rem & 7;            // 0..7
    int p  = pp * 8 + xcd;       // 0..15
    int mt = r * 16 + p;         // 0..127
    const int bm = mt * BMT;
    const int bn = nt * BNT;

    f32x4 acc[4][4] = {};
    bf16x8 af[2][2], bfr[4][2];

    // ---- staging: dest LINEAR, source XOR-swizzled (inverse of read swizzle) ----
    auto stageA = [&](int kt, int buf, int part) { // 2 loads; rows 128B = 8 chunks
        #pragma unroll
        for (int j = 2 * part; j < 2 * part + 2; ++j) {
            int idx = j * 512 + t;             // 0..2047
            int row = idx >> 3;
            int s = idx & 7;
            int c = s ^ (row & 7);
            const ushort_t* g = Abf + (size_t)(bm + row) * KP + kt * 64 + c * 8;
            ushort_t* lp = &lA[buf][(idx & ~63) * 8];
            __builtin_amdgcn_global_load_lds((const AS1 void*)g, (AS3 void*)lp, 16, 0, 0);
        }
    };
    auto stageB = [&](int kt, int buf) { // 2 loads
        #pragma unroll
        for (int j = 0; j < 2; ++j) {
            int idx = j * 512 + t;             // 0..1023
            int row = idx >> 3;
            int s = idx & 7;
            int c = s ^ (row & 7);
            const ushort_t* g = Bbf + (size_t)(bn + row) * KP + kt * 64 + c * 8;
            ushort_t* lp = &lB[buf][(idx & ~63) * 8];
            __builtin_amdgcn_global_load_lds((const AS1 void*)g, (AS3 void*)lp, 16, 0, 0);
        }
    };
    auto stageAtail = [&]() { // 2 loads; 64B rows, proven slot^((row>>1)&3)
        #pragma unroll
        for (int j = 0; j < 2; ++j) {
            int idx = j * 512 + t;             // 0..1023
            int row = idx >> 2;
            int s = idx & 3;
            int c = s ^ ((row >> 1) & 3);
            const ushort_t* g = Abf + (size_t)(bm + row) * KP + KTAIL + c * 8;
            ushort_t* lp = &lAt[(idx & ~63) * 8];
            __builtin_amdgcn_global_load_lds((const AS1 void*)g, (AS3 void*)lp, 16, 0, 0);
        }
    };
    auto stageBtail = [&]() { // 1 load
        int idx = t;                            // 0..511
        int row = idx >> 2;
        int s = idx & 3;
        int c = s ^ ((row >> 1) & 3);
        const ushort_t* g = Bbf + (size_t)(bn + row) * KP + KTAIL + c * 8;
        ushort_t* lp = &lBt[(idx & ~63) * 8];
        __builtin_amdgcn_global_load_lds((const AS1 void*)g, (AS3 void*)lp, 16, 0, 0);
    };

    // ---- fragment reads (swizzled; 2-way bank alias = free) ----
    auto rdA = [&](int buf, int mi, int kh) -> bf16x8 {
        int row = wm * 64 + mi * 16 + lm;
        int slot = ((kh << 2) | lq) ^ (row & 7);
        return *(const bf16x8*)(&lA[buf][row * 64 + slot * 8]);
    };
    auto rdB = [&](int buf, int ni, int kh) -> bf16x8 {
        int row = wn * 64 + ni * 16 + lm;
        int slot = ((kh << 2) | lq) ^ (row & 7);
        return *(const bf16x8*)(&lB[buf][row * 64 + slot * 8]);
    };
    auto rdAt = [&](int mi) -> bf16x8 {
        int row = wm * 64 + mi * 16 + lm;
        int slot = lq ^ ((row >> 1) & 3);
        return *(const bf16x8*)(&lAt[row * 32 + slot * 8]);
    };
    auto rdBt = [&](int ni) -> bf16x8 {
        int row = wn * 64 + ni * 16 + lm;
        int slot = lq ^ ((row >> 1) & 3);
        return *(const bf16x8*)(&lBt[row * 32 + slot * 8]);
    };

    // prologue: tile 0 fully in flight (6 loads)
    stageA(0, 0, 0); stageA(0, 0, 1); stageB(0, 0);

    for (int kt = 0; kt < NFULL; ++kt) {
        const int cur = kt & 1, nxt = cur ^ 1;
        const bool last = (kt == NFULL - 1);

        // ---- top: issue 2 loads of next tile, gate tile kt (counted!) ----
        if (!last) stageA(kt + 1, nxt, 0); else stageAtail();
        asm volatile("s_waitcnt vmcnt(2)" ::: "memory"); // tile kt's 6 landed; 2 fly
        __builtin_amdgcn_s_barrier();
        __builtin_amdgcn_sched_barrier(0);

        // ---- phase 0: A(mq0) + B(nq0) reads, 2 stage, MFMA (mi01 x ni01) ----
        af[0][0] = rdA(cur, 0, 0); af[0][1] = rdA(cur, 0, 1);
        af[1][0] = rdA(cur, 1, 0); af[1][1] = rdA(cur, 1, 1);
        bfr[0][0] = rdB(cur, 0, 0); bfr[0][1] = rdB(cur, 0, 1);
        bfr[1][0] = rdB(cur, 1, 0); bfr[1][1] = rdB(cur, 1, 1);
        if (!last) stageA(kt + 1, nxt, 1); else stageBtail();
        asm volatile("s_waitcnt lgkmcnt(0)" ::: "memory");
        __builtin_amdgcn_sched_barrier(0);
        __builtin_amdgcn_s_setprio(1);
        MFMA_(0,0,0,0) MFMA_(0,0,0,1) MFMA_(0,1,0,0) MFMA_(0,1,0,1)
        MFMA_(1,0,1,0) MFMA_(1,0,1,1) MFMA_(1,1,1,0) MFMA_(1,1,1,1)
        __builtin_amdgcn_s_setprio(0);
        __builtin_amdgcn_sched_barrier(0);
        __builtin_amdgcn_s_barrier();

        // ---- phase 1: B(nq1) reads, 2 stage, MFMA (mi01 x ni23) ----
        bfr[2][0] = rdB(cur, 2, 0); bfr[2][1] = rdB(cur, 2, 1);
        bfr[3][0] = rdB(cur, 3, 0); bfr[3][1] = rdB(cur, 3, 1);
        if (!last) stageB(kt + 1, nxt);
        asm volatile("s_waitcnt lgkmcnt(0)" ::: "memory");
        __builtin_amdgcn_sched_barrier(0);
        __builtin_amdgcn_s_setprio(1);
        MFMA_(0,2,0,0) MFMA_(0,2,0,1) MFMA_(0,3,0,0) MFMA_(0,3,0,1)
        MFMA_(1,2,1,0) MFMA_(1,2,1,1) MFMA_(1,3,1,0) MFMA_(1,3,1,1)
        __builtin_amdgcn_s_setprio(0);
        __builtin_amdgcn_sched_barrier(0);
        __builtin_amdgcn_s_barrier();

        // ---- phase 2: A(mq1) reads, MFMA (mi23 x ni01) ----
        af[0][0] = rdA(cur, 2, 0); af[0][1] = rdA(cur, 2, 1);
        af[1][0] = rdA(cur, 3, 0); af[1][1] = rdA(cur, 3, 1);
        asm volatile("s_waitcnt lgkmcnt(0)" ::: "memory");
        __builtin_amdgcn_sched_barrier(0);
        __builtin_amdgcn_s_setprio(1);
        MFMA_(2,0,0,0) MFMA_(2,0,0,1) MFMA_(2,1,0,0) MFMA_(2,1,0,1)
        MFMA_(3,0,1,0) MFMA_(3,0,1,1) MFMA_(3,1,1,0) MFMA_(3,1,1,1)
        __builtin_amdgcn_s_setprio(0);
        __builtin_amdgcn_sched_barrier(0);
        __builtin_amdgcn_s_barrier();

        // ---- phase 3: MFMA (mi23 x ni23); end barrier frees buf cur ----
        __builtin_amdgcn_s_setprio(1);
        MFMA_(2,2,0,0) MFMA_(2,2,0,1) MFMA_(2,3,0,0) MFMA_(2,3,0,1)
        MFMA_(3,2,1,0) MFMA_(3,2,1,1) MFMA_(3,3,1,0) MFMA_(3,3,1,1)
        __builtin_amdgcn_s_setprio(0);
        __builtin_amdgcn_sched_barrier(0);
        __builtin_amdgcn_s_barrier();
    }

    // ---- tail K-tile (k 576..607, 32 wide: B kh=0 only; af 2nd idx = mi) ----
    asm volatile("s_waitcnt vmcnt(0)" ::: "memory");
    __builtin_amdgcn_s_barrier();
    __builtin_amdgcn_sched_barrier(0);
    af[0][0] = rdAt(0); af[0][1] = rdAt(1); af[1][0] = rdAt(2); af[1][1] = rdAt(3);
    bfr[0][0] = rdBt(0); bfr[1][0] = rdBt(1); bfr[2][0] = rdBt(2); bfr[3][0] = rdBt(3);
    asm volatile("s_waitcnt lgkmcnt(0)" ::: "memory");
    __builtin_amdgcn_sched_barrier(0);
    __builtin_amdgcn_s_setprio(1);
    MFMT_(0,0,0,0) MFMT_(0,1,0,0) MFMT_(0,2,0,0) MFMT_(0,3,0,0)
    MFMT_(1,0,0,1) MFMT_(1,1,0,1) MFMT_(1,2,0,1) MFMT_(1,3,0,1)
    MFMT_(2,0,1,0) MFMT_(2,1,1,0) MFMT_(2,2,1,0) MFMT_(2,3,1,0)
    MFMT_(3,0,1,1) MFMT_(3,1,1,1) MFMT_(3,2,1,1) MFMT_(3,3,1,1)
    __builtin_amdgcn_s_setprio(0);

    // epilogue: swapped C-layout -> lane holds out[m][nb..nb+3]; bias folded in pos
    const int M0 = bm + wm * 64;
    const int N0 = bn + wn * 64;
    #pragma unroll
    for (int mi = 0; mi < 4; ++mi) {
        int m = M0 + mi * 16 + lm;
        const float* posrow = pos + (size_t)(m & (POSROWS - 1)) * NN;
        float* outrow = out + (size_t)m * NN;
        #pragma unroll
        for (int ni = 0; ni < 4; ++ni) {
            int nb = N0 + ni * 16 + lq * 4;
            f32x4 pv4 = *(const f32x4*)(posrow + nb);
            f32x4 v = acc[mi][ni];
            v.x += pv4.x; v.y += pv4.y; v.z += pv4.z; v.w += pv4.w;
            *(f32x4*)(outrow + nb) = v;
        }
    }
}

// ---------------- fallback (ws too small): naive fp32 ----------------

__global__ void fb_kernel(const float* __restrict__ A, const float* __restrict__ W,
                          const float* __restrict__ bias, const float* __restrict__ pt,
                          float* __restrict__ out) {
    __shared__ float sA[16][17], sB[16][17];
    int ty = threadIdx.y, tx = threadIdx.x;
    int row = blockIdx.y * 16 + ty; // M
    int col = blockIdx.x * 16 + tx; // N
    float acc = 0.f;
    for (int k0 = 0; k0 < KK; k0 += 16) {
        int ka = k0 + tx;
        sA[ty][tx] = (ka < KK) ? A[(size_t)row * KK + ka] : 0.f;
        sB[ty][tx] = (ka < KK) ? W[(size_t)(blockIdx.x * 16 + ty) * KK + ka] : 0.f;
        __syncthreads();
        #pragma unroll
        for (int kk = 0; kk < 16; ++kk)
            acc += sA[ty][kk] * sB[tx][kk];
        __syncthreads();
    }
    int n = row & (POSROWS - 1);
    int h = ((n >> 7) << 1) | ((n >> 1) & 1);
    int w = (((n >> 2) & 31) << 1) | (n & 1);
    float wh[4], ww[4]; int ih[4], iw[4];
    cubic_taps(h, wh, ih);
    cubic_taps(w, ww, iw);
    float pq = 0.f;
    #pragma unroll
    for (int a = 0; a < 4; ++a) {
        float rs = 0.f;
        #pragma unroll
        for (int b = 0; b < 4; ++b)
            rs += ww[b] * pt[(ih[a] * 16 + iw[b]) * NN + col];
        pq += wh[a] * rs;
    }
    out[(size_t)row * NN + col] = acc + bias[col] + pq;
}

// ---------------- launch ----------------

extern "C" void kernel_launch(void* const* d_in, const int* in_sizes, int n_in,
                              void* d_out, int out_size, void* d_ws, size_t ws_size,
                              hipStream_t stream) {
    const float* pv   = (const float*)d_in[0]; // (32768, 588)
    const float* wp   = (const float*)d_in[1]; // (1152, 588)
    const float* bias = (const float*)d_in[2]; // (1152,)
    const float* pt   = (const float*)d_in[3]; // (256, 1152)
    float* out = (float*)d_out;

    const size_t pos_bytes = (size_t)POSROWS * NN * 4;   // 18,874,368
    const size_t pvb_bytes = (size_t)MM * KP * 2;        // 39,845,888
    const size_t wb_bytes  = (size_t)NN * KP * 2;        //  1,400,832
    const size_t need = pos_bytes + pvb_bytes + wb_bytes;

    if (ws_size >= need) {
        float* pos = (float*)d_ws;
        ushort_t* pvb = (ushort_t*)((char*)d_ws + pos_bytes);
        ushort_t* wb  = (ushort_t*)((char*)d_ws + pos_bytes + pvb_bytes);

        prep_kernel<<<ABLOCKS + BBLOCKS + POSROWS, 256, 0, stream>>>(
            pv, pvb, wp, wb, pt, bias, pos);
        gemm_kernel<<<GRID, 512, 0, stream>>>(pvb, wb, pos, out);
    } else {
        fb_kernel<<<dim3(NN / 16, MM / 16), dim3(16, 16), 0, stream>>>(pv, wp, bias, pt, out);
    }
}